// Round 3
// baseline (95.570 us; speedup 1.0000x reference)
//
#include <hip/hip_runtime.h>
#include <hip/hip_cooperative_groups.h>
#include <math.h>

namespace cg = cooperative_groups;

// Forward kinematics as an associative scan over affine pairs (M, p):
//   elem_j = (R_j, l_j * R_j[:,2]);  (M1,p1) ⊗ (M2,p2) = (M1*M2, p1 + M1*p2)
// Output_i = p-component of inclusive prefix up to i.
//
// Single cooperative kernel: local scan -> grid.sync -> per-block redundant
// prefix-reduce of block aggregates -> apply + write. Fallback: 3-kernel scan.

#define TPB 256          // threads per block
#define EPT 4            // elements per thread
#define EPB (TPB * EPT)  // 1024 elements per block
#define MAXB 1024        // max blocks (N = 2^20 / 1024)

struct Xf {
    float m[9];  // row-major 3x3
    float p[3];
};

__device__ __forceinline__ void xf_identity(Xf& x) {
    x.m[0] = 1.f; x.m[1] = 0.f; x.m[2] = 0.f;
    x.m[3] = 0.f; x.m[4] = 1.f; x.m[5] = 0.f;
    x.m[6] = 0.f; x.m[7] = 0.f; x.m[8] = 1.f;
    x.p[0] = 0.f; x.p[1] = 0.f; x.p[2] = 0.f;
}

// out = A ⊗ B  (A is the earlier prefix)
__device__ __forceinline__ Xf xf_comb(const Xf& A, const Xf& B) {
    Xf o;
#pragma unroll
    for (int r = 0; r < 3; ++r) {
        const float a0 = A.m[r * 3 + 0], a1 = A.m[r * 3 + 1], a2 = A.m[r * 3 + 2];
#pragma unroll
        for (int c = 0; c < 3; ++c) {
            o.m[r * 3 + c] = a0 * B.m[0 * 3 + c] + a1 * B.m[1 * 3 + c] + a2 * B.m[2 * 3 + c];
        }
        o.p[r] = A.p[r] + a0 * B.p[0] + a1 * B.p[1] + a2 * B.p[2];
    }
    return o;
}

// a = a ⊗ elem(theta=(ax,ay,az), l).  R = Rz@Ry@Rx (ZYX Euler).
// ACCURATE sincosf (ocml ~1ulp): fast __sincosf random-walks past the 2% threshold.
__device__ __forceinline__ void xf_fold(Xf& a, float ax, float ay, float az, float l) {
    float sx, cx, sy, cy, sz, cz;
    sincosf(ax, &sx, &cx);
    sincosf(ay, &sy, &cy);
    sincosf(az, &sz, &cz);
    const float sysx = sy * sx, sycx = sy * cx;
    const float r00 = cz * cy;
    const float r01 = cz * sysx - sz * cx;
    const float r02 = sz * sx + cz * sycx;
    const float r10 = sz * cy;
    const float r11 = cz * cx + sz * sysx;
    const float r12 = sz * sycx - cz * sx;
    const float r20 = -sy;
    const float r21 = cy * sx;
    const float r22 = cy * cx;
    const float t0 = l * r02, t1 = l * r12, t2 = l * r22;
    const float p0 = a.p[0] + a.m[0] * t0 + a.m[1] * t1 + a.m[2] * t2;
    const float p1 = a.p[1] + a.m[3] * t0 + a.m[4] * t1 + a.m[5] * t2;
    const float p2 = a.p[2] + a.m[6] * t0 + a.m[7] * t1 + a.m[8] * t2;
    const float n0 = a.m[0] * r00 + a.m[1] * r10 + a.m[2] * r20;
    const float n1 = a.m[0] * r01 + a.m[1] * r11 + a.m[2] * r21;
    const float n2 = a.m[0] * r02 + a.m[1] * r12 + a.m[2] * r22;
    const float n3 = a.m[3] * r00 + a.m[4] * r10 + a.m[5] * r20;
    const float n4 = a.m[3] * r01 + a.m[4] * r11 + a.m[5] * r21;
    const float n5 = a.m[3] * r02 + a.m[4] * r12 + a.m[5] * r22;
    const float n6 = a.m[6] * r00 + a.m[7] * r10 + a.m[8] * r20;
    const float n7 = a.m[6] * r01 + a.m[7] * r11 + a.m[8] * r21;
    const float n8 = a.m[6] * r02 + a.m[7] * r12 + a.m[8] * r22;
    a.m[0] = n0; a.m[1] = n1; a.m[2] = n2;
    a.m[3] = n3; a.m[4] = n4; a.m[5] = n5;
    a.m[6] = n6; a.m[7] = n7; a.m[8] = n8;
    a.p[0] = p0; a.p[1] = p1; a.p[2] = p2;
}

// ---- LDS scan helpers: 13-dword stride (odd) -> only free 2-way bank aliasing ----
typedef float ShRow[13];

__device__ __forceinline__ void sh_store(ShRow* sh, int t, const Xf& a) {
#pragma unroll
    for (int k = 0; k < 9; ++k) sh[t][k] = a.m[k];
    sh[t][9] = a.p[0]; sh[t][10] = a.p[1]; sh[t][11] = a.p[2];
}
__device__ __forceinline__ Xf sh_load(const ShRow* sh, int t) {
    Xf a;
#pragma unroll
    for (int k = 0; k < 9; ++k) a.m[k] = sh[t][k];
    a.p[0] = sh[t][9]; a.p[1] = sh[t][10]; a.p[2] = sh[t][11];
    return a;
}

// Inclusive Hillis-Steele block scan. On exit sh holds inclusive values
// (barrier done); returns this thread's inclusive value.
__device__ __forceinline__ Xf block_scan(Xf a, ShRow* sh, int t) {
    sh_store(sh, t, a);
    for (int off = 1; off < TPB; off <<= 1) {
        __syncthreads();
        Xf b;
        const bool act = (t >= off);
        if (act) b = sh_load(sh, t - off);
        __syncthreads();
        if (act) { a = xf_comb(b, a); sh_store(sh, t, a); }
    }
    __syncthreads();
    return a;
}

// ---- local fold of EPT elements, recording per-element positions ----
__device__ __forceinline__ void local_fold(const float* __restrict__ ll,
                                           const float* __restrict__ th,
                                           long long j0, int n, Xf& a,
                                           float pe[EPT][3]) {
    xf_identity(a);
    if (j0 + EPT <= n) {
        const float4* th4 = (const float4*)(th + 3 * j0);
        const float4 A = th4[0], B = th4[1], C = th4[2];
        const float4 L = *(const float4*)(ll + j0);
        xf_fold(a, A.x, A.y, A.z, L.x);
        pe[0][0] = a.p[0]; pe[0][1] = a.p[1]; pe[0][2] = a.p[2];
        xf_fold(a, A.w, B.x, B.y, L.y);
        pe[1][0] = a.p[0]; pe[1][1] = a.p[1]; pe[1][2] = a.p[2];
        xf_fold(a, B.z, B.w, C.x, L.z);
        pe[2][0] = a.p[0]; pe[2][1] = a.p[1]; pe[2][2] = a.p[2];
        xf_fold(a, C.y, C.z, C.w, L.w);
        pe[3][0] = a.p[0]; pe[3][1] = a.p[1]; pe[3][2] = a.p[2];
    } else {
#pragma unroll
        for (int e = 0; e < EPT; ++e) {
            const long long j = j0 + e;
            if (j < n) xf_fold(a, th[3 * j + 0], th[3 * j + 1], th[3 * j + 2], ll[j]);
            pe[e][0] = a.p[0]; pe[e][1] = a.p[1]; pe[e][2] = a.p[2];
        }
    }
}

__device__ __forceinline__ void write_out(float* __restrict__ out, long long j0, int n,
                                          const Xf& T, const float pe[EPT][3]) {
    if (j0 + EPT <= n) {
        float o[EPT * 3];
#pragma unroll
        for (int e = 0; e < EPT; ++e) {
            const float q0 = pe[e][0], q1 = pe[e][1], q2 = pe[e][2];
            o[e * 3 + 0] = T.p[0] + T.m[0] * q0 + T.m[1] * q1 + T.m[2] * q2;
            o[e * 3 + 1] = T.p[1] + T.m[3] * q0 + T.m[4] * q1 + T.m[5] * q2;
            o[e * 3 + 2] = T.p[2] + T.m[6] * q0 + T.m[7] * q1 + T.m[8] * q2;
        }
        float4* o4 = (float4*)(out + 3 * j0);
        o4[0] = make_float4(o[0], o[1], o[2], o[3]);
        o4[1] = make_float4(o[4], o[5], o[6], o[7]);
        o4[2] = make_float4(o[8], o[9], o[10], o[11]);
    } else {
#pragma unroll
        for (int e = 0; e < EPT; ++e) {
            const long long j = j0 + e;
            if (j < n) {
                const float q0 = pe[e][0], q1 = pe[e][1], q2 = pe[e][2];
                out[3 * j + 0] = T.p[0] + T.m[0] * q0 + T.m[1] * q1 + T.m[2] * q2;
                out[3 * j + 1] = T.p[1] + T.m[3] * q0 + T.m[4] * q1 + T.m[5] * q2;
                out[3 * j + 2] = T.p[2] + T.m[6] * q0 + T.m[7] * q1 + T.m[8] * q2;
            }
        }
    }
}

// ================= fused cooperative kernel =================
__global__ void __launch_bounds__(TPB, 4)
fk_fused(const float* __restrict__ ll, const float* __restrict__ th,
         Xf* __restrict__ agg, float* __restrict__ out, int n) {
    __shared__ ShRow sh[TPB];
    const int t = threadIdx.x, bid = blockIdx.x;
    const long long j0 = (long long)bid * EPB + (long long)t * EPT;

    Xf a;
    float pe[EPT][3];
    local_fold(ll, th, j0, n, a, pe);

    const Xf inc = block_scan(a, sh, t);
    Xf ex;                                       // thread-exclusive prefix in block
    if (t == 0) xf_identity(ex); else ex = sh_load(sh, t - 1);
    if (t == TPB - 1) agg[bid] = inc;            // block inclusive aggregate

    cg::this_grid().sync();

    // Each block redundantly computes G = agg[0] ⊗ ... ⊗ agg[bid-1].
    Xf acc;
    xf_identity(acc);
    {
        const int i0 = t * EPT;
#pragma unroll
        for (int e = 0; e < EPT; ++e) {
            const int i = i0 + e;
            if (i < bid) {
                const float4* g4 = (const float4*)&agg[i];
                const float4 x = g4[0], y = g4[1], z = g4[2];
                Xf b;
                b.m[0] = x.x; b.m[1] = x.y; b.m[2] = x.z;
                b.m[3] = x.w; b.m[4] = y.x; b.m[5] = y.y;
                b.m[6] = y.z; b.m[7] = y.w; b.m[8] = z.x;
                b.p[0] = z.y; b.p[1] = z.z; b.p[2] = z.w;
                acc = xf_comb(acc, b);
            }
        }
    }
    __syncthreads();  // sh reuse (ex already in regs)
    block_scan(acc, sh, t);
    const Xf G = sh_load(sh, TPB - 1);           // product over [0, bid)

    const Xf T = xf_comb(G, ex);
    write_out(out, j0, n, T, pe);
}

// ================= fallback: 3-kernel scan =================
__global__ void __launch_bounds__(TPB) fk_phase1(const float* __restrict__ ll,
                                                 const float* __restrict__ th,
                                                 Xf* __restrict__ agg, int n) {
    __shared__ ShRow sh[TPB];
    const int t = threadIdx.x;
    const long long j0 = (long long)blockIdx.x * EPB + (long long)t * EPT;
    Xf a;
    float pe[EPT][3];
    local_fold(ll, th, j0, n, a, pe);
    const Xf inc = block_scan(a, sh, t);
    if (t == TPB - 1) agg[blockIdx.x] = inc;
}

__global__ void fk_phase2(Xf* __restrict__ agg, Xf* __restrict__ pfx, int nb) {
    __shared__ float sh2[1024][13];
    const int t = threadIdx.x;
    Xf a;
    if (t < nb) a = agg[t]; else xf_identity(a);
    sh_store(sh2, t, a);
    for (int off = 1; off < (int)blockDim.x; off <<= 1) {
        __syncthreads();
        Xf b;
        const bool act = (t >= off);
        if (act) b = sh_load(sh2, t - off);
        __syncthreads();
        if (act) { a = xf_comb(b, a); sh_store(sh2, t, a); }
    }
    __syncthreads();
    Xf ex;
    if (t == 0) xf_identity(ex); else ex = sh_load(sh2, t - 1);
    if (t < nb) pfx[t] = ex;
}

__global__ void __launch_bounds__(TPB) fk_phase3(const float* __restrict__ ll,
                                                 const float* __restrict__ th,
                                                 const Xf* __restrict__ pfx,
                                                 float* __restrict__ out, int n) {
    __shared__ ShRow sh[TPB];
    const int t = threadIdx.x;
    const long long j0 = (long long)blockIdx.x * EPB + (long long)t * EPT;
    Xf a;
    float pe[EPT][3];
    local_fold(ll, th, j0, n, a, pe);
    block_scan(a, sh, t);
    Xf ex;
    if (t == 0) xf_identity(ex); else ex = sh_load(sh, t - 1);
    const Xf G = pfx[blockIdx.x];
    const Xf T = xf_comb(G, ex);
    write_out(out, j0, n, T, pe);
}

extern "C" void kernel_launch(void* const* d_in, const int* in_sizes, int n_in,
                              void* d_out, int out_size, void* d_ws, size_t ws_size,
                              hipStream_t stream) {
    const float* ll = (const float*)d_in[0];   // link_lengths [N]
    const float* th = (const float*)d_in[1];   // theta [N,3]
    float* out = (float*)d_out;                // [N,3] f32
    int n = in_sizes[0];

    int nb = (n + EPB - 1) / EPB;              // 1024 for N = 2^20
    if (nb > MAXB) nb = MAXB;

    Xf* agg = (Xf*)d_ws;
    Xf* pfx = agg + MAXB;

    void* args[] = {(void*)&ll, (void*)&th, (void*)&agg, (void*)&out, (void*)&n};
    hipError_t err = hipLaunchCooperativeKernel((const void*)fk_fused, dim3(nb), dim3(TPB),
                                                args, 0, stream);
    if (err != hipSuccess) {
        // Fallback: 3-kernel decomposition (no grid sync needed).
        fk_phase1<<<nb, TPB, 0, stream>>>(ll, th, agg, n);
        fk_phase2<<<1, nb, 0, stream>>>(agg, pfx, nb);
        fk_phase3<<<nb, TPB, 0, stream>>>(ll, th, pfx, out, n);
    }
}

// Round 4
// 32.298 us; speedup vs baseline: 2.9590x; 2.9590x over previous
//
#include <hip/hip_runtime.h>
#include <math.h>

// Forward kinematics as an associative scan over affine pairs (M, p):
//   elem_j = (R_j, l_j * R_j[:,2]);  (M1,p1) ⊗ (M2,p2) = (M1*M2, p1 + M1*p2)
// Output_i = p-component of inclusive prefix up to i.
//
// R3 structure: 3-kernel scan, but the block scan is a barrier-free
// wave-shuffle scan (6 shfl_up rounds) + one-barrier cross-wave fixup with
// broadcast LDS reads. The R2 LDS Hillis-Steele scan (192 scalar LDS ops +
// 16 barriers per scan) was the dominant cost.

#define TPB 256          // threads per block
#define EPT 4            // elements per thread
#define EPB (TPB * EPT)  // 1024 elements per block
#define MAXB 1024        // max blocks (N = 2^20 / 1024)
#define NWAVE (TPB / 64)

struct Xf {
    float m[9];  // row-major 3x3
    float p[3];
};

__device__ __forceinline__ void xf_identity(Xf& x) {
    x.m[0] = 1.f; x.m[1] = 0.f; x.m[2] = 0.f;
    x.m[3] = 0.f; x.m[4] = 1.f; x.m[5] = 0.f;
    x.m[6] = 0.f; x.m[7] = 0.f; x.m[8] = 1.f;
    x.p[0] = 0.f; x.p[1] = 0.f; x.p[2] = 0.f;
}

// out = A ⊗ B  (A is the earlier prefix)
__device__ __forceinline__ Xf xf_comb(const Xf& A, const Xf& B) {
    Xf o;
#pragma unroll
    for (int r = 0; r < 3; ++r) {
        const float a0 = A.m[r * 3 + 0], a1 = A.m[r * 3 + 1], a2 = A.m[r * 3 + 2];
#pragma unroll
        for (int c = 0; c < 3; ++c) {
            o.m[r * 3 + c] = a0 * B.m[0 * 3 + c] + a1 * B.m[1 * 3 + c] + a2 * B.m[2 * 3 + c];
        }
        o.p[r] = A.p[r] + a0 * B.p[0] + a1 * B.p[1] + a2 * B.p[2];
    }
    return o;
}

// a = a ⊗ elem(theta=(ax,ay,az), l).  R = Rz@Ry@Rx (ZYX Euler).
// ACCURATE sincosf (ocml ~1ulp): fast __sincosf random-walks past the 2% threshold.
__device__ __forceinline__ void xf_fold(Xf& a, float ax, float ay, float az, float l) {
    float sx, cx, sy, cy, sz, cz;
    sincosf(ax, &sx, &cx);
    sincosf(ay, &sy, &cy);
    sincosf(az, &sz, &cz);
    const float sysx = sy * sx, sycx = sy * cx;
    const float r00 = cz * cy;
    const float r01 = cz * sysx - sz * cx;
    const float r02 = sz * sx + cz * sycx;
    const float r10 = sz * cy;
    const float r11 = cz * cx + sz * sysx;
    const float r12 = sz * sycx - cz * sx;
    const float r20 = -sy;
    const float r21 = cy * sx;
    const float r22 = cy * cx;
    const float t0 = l * r02, t1 = l * r12, t2 = l * r22;
    const float p0 = a.p[0] + a.m[0] * t0 + a.m[1] * t1 + a.m[2] * t2;
    const float p1 = a.p[1] + a.m[3] * t0 + a.m[4] * t1 + a.m[5] * t2;
    const float p2 = a.p[2] + a.m[6] * t0 + a.m[7] * t1 + a.m[8] * t2;
    const float n0 = a.m[0] * r00 + a.m[1] * r10 + a.m[2] * r20;
    const float n1 = a.m[0] * r01 + a.m[1] * r11 + a.m[2] * r21;
    const float n2 = a.m[0] * r02 + a.m[1] * r12 + a.m[2] * r22;
    const float n3 = a.m[3] * r00 + a.m[4] * r10 + a.m[5] * r20;
    const float n4 = a.m[3] * r01 + a.m[4] * r11 + a.m[5] * r21;
    const float n5 = a.m[3] * r02 + a.m[4] * r12 + a.m[5] * r22;
    const float n6 = a.m[6] * r00 + a.m[7] * r10 + a.m[8] * r20;
    const float n7 = a.m[6] * r01 + a.m[7] * r11 + a.m[8] * r21;
    const float n8 = a.m[6] * r02 + a.m[7] * r12 + a.m[8] * r22;
    a.m[0] = n0; a.m[1] = n1; a.m[2] = n2;
    a.m[3] = n3; a.m[4] = n4; a.m[5] = n5;
    a.m[6] = n6; a.m[7] = n7; a.m[8] = n8;
    a.p[0] = p0; a.p[1] = p1; a.p[2] = p2;
}

// ---- wave shuffle helpers ----
__device__ __forceinline__ Xf xf_shfl_up(const Xf& a, int delta) {
    Xf o;
#pragma unroll
    for (int k = 0; k < 9; ++k) o.m[k] = __shfl_up(a.m[k], delta, 64);
#pragma unroll
    for (int k = 0; k < 3; ++k) o.p[k] = __shfl_up(a.p[k], delta, 64);
    return o;
}

// Inclusive scan across the 64-lane wave (no barriers, no LDS).
__device__ __forceinline__ Xf wave_scan(Xf a, int lane) {
#pragma unroll
    for (int off = 1; off < 64; off <<= 1) {
        const Xf b = xf_shfl_up(a, off);
        if (lane >= off) a = xf_comb(b, a);
    }
    return a;
}

// ---- Xf <-> global as 3x float4 (Xf is 12 consecutive floats) ----
__device__ __forceinline__ Xf xf_load4(const Xf* p) {
    const float4* g = (const float4*)p;
    const float4 x = g[0], y = g[1], z = g[2];
    Xf b;
    b.m[0] = x.x; b.m[1] = x.y; b.m[2] = x.z;
    b.m[3] = x.w; b.m[4] = y.x; b.m[5] = y.y;
    b.m[6] = y.z; b.m[7] = y.w; b.m[8] = z.x;
    b.p[0] = z.y; b.p[1] = z.z; b.p[2] = z.w;
    return b;
}
__device__ __forceinline__ void xf_store4(Xf* p, const Xf& b) {
    float4* g = (float4*)p;
    g[0] = make_float4(b.m[0], b.m[1], b.m[2], b.m[3]);
    g[1] = make_float4(b.m[4], b.m[5], b.m[6], b.m[7]);
    g[2] = make_float4(b.m[8], b.p[0], b.p[1], b.p[2]);
}

// ---- local fold of EPT elements, recording per-element positions ----
__device__ __forceinline__ void local_fold(const float* __restrict__ ll,
                                           const float* __restrict__ th,
                                           long long j0, int n, Xf& a,
                                           float pe[EPT][3]) {
    xf_identity(a);
    if (j0 + EPT <= n) {
        const float4* th4 = (const float4*)(th + 3 * j0);
        const float4 A = th4[0], B = th4[1], C = th4[2];
        const float4 L = *(const float4*)(ll + j0);
        xf_fold(a, A.x, A.y, A.z, L.x);
        pe[0][0] = a.p[0]; pe[0][1] = a.p[1]; pe[0][2] = a.p[2];
        xf_fold(a, A.w, B.x, B.y, L.y);
        pe[1][0] = a.p[0]; pe[1][1] = a.p[1]; pe[1][2] = a.p[2];
        xf_fold(a, B.z, B.w, C.x, L.z);
        pe[2][0] = a.p[0]; pe[2][1] = a.p[1]; pe[2][2] = a.p[2];
        xf_fold(a, C.y, C.z, C.w, L.w);
        pe[3][0] = a.p[0]; pe[3][1] = a.p[1]; pe[3][2] = a.p[2];
    } else {
#pragma unroll
        for (int e = 0; e < EPT; ++e) {
            const long long j = j0 + e;
            if (j < n) xf_fold(a, th[3 * j + 0], th[3 * j + 1], th[3 * j + 2], ll[j]);
            pe[e][0] = a.p[0]; pe[e][1] = a.p[1]; pe[e][2] = a.p[2];
        }
    }
}

__device__ __forceinline__ void write_out(float* __restrict__ out, long long j0, int n,
                                          const Xf& T, const float pe[EPT][3]) {
    if (j0 + EPT <= n) {
        float o[EPT * 3];
#pragma unroll
        for (int e = 0; e < EPT; ++e) {
            const float q0 = pe[e][0], q1 = pe[e][1], q2 = pe[e][2];
            o[e * 3 + 0] = T.p[0] + T.m[0] * q0 + T.m[1] * q1 + T.m[2] * q2;
            o[e * 3 + 1] = T.p[1] + T.m[3] * q0 + T.m[4] * q1 + T.m[5] * q2;
            o[e * 3 + 2] = T.p[2] + T.m[6] * q0 + T.m[7] * q1 + T.m[8] * q2;
        }
        float4* o4 = (float4*)(out + 3 * j0);
        o4[0] = make_float4(o[0], o[1], o[2], o[3]);
        o4[1] = make_float4(o[4], o[5], o[6], o[7]);
        o4[2] = make_float4(o[8], o[9], o[10], o[11]);
    } else {
#pragma unroll
        for (int e = 0; e < EPT; ++e) {
            const long long j = j0 + e;
            if (j < n) {
                const float q0 = pe[e][0], q1 = pe[e][1], q2 = pe[e][2];
                out[3 * j + 0] = T.p[0] + T.m[0] * q0 + T.m[1] * q1 + T.m[2] * q2;
                out[3 * j + 1] = T.p[1] + T.m[3] * q0 + T.m[4] * q1 + T.m[5] * q2;
                out[3 * j + 2] = T.p[2] + T.m[6] * q0 + T.m[7] * q1 + T.m[8] * q2;
            }
        }
    }
}

// ---------------- Phase 1: per-block aggregates ----------------
__global__ void __launch_bounds__(TPB) fk_phase1(const float* __restrict__ ll,
                                                 const float* __restrict__ th,
                                                 Xf* __restrict__ agg, int n) {
    __shared__ Xf wagg[NWAVE];
    const int t = threadIdx.x;
    const int lane = t & 63, w = t >> 6;
    const long long j0 = (long long)blockIdx.x * EPB + (long long)t * EPT;

    Xf a;
    float pe[EPT][3];  // unused here (DCE'd)
    local_fold(ll, th, j0, n, a, pe);

    const Xf inc = wave_scan(a, lane);
    if (lane == 63) wagg[w] = inc;
    __syncthreads();

    if (t == TPB - 1) {
        // block aggregate = wagg[0] ⊗ ... ⊗ wagg[NWAVE-2] ⊗ inc
        Xf acc = wagg[0];
#pragma unroll
        for (int k = 1; k < NWAVE - 1; ++k) acc = xf_comb(acc, wagg[k]);
        acc = xf_comb(acc, inc);
        xf_store4(&agg[blockIdx.x], acc);
    }
}

// ---------------- Phase 2: scan block aggregates (one 256-thread block) ----------------
__global__ void __launch_bounds__(TPB) fk_phase2(const Xf* __restrict__ agg,
                                                 Xf* __restrict__ pfx, int nb) {
    __shared__ Xf wagg[NWAVE];
    const int t = threadIdx.x;
    const int lane = t & 63, w = t >> 6;
    const int i0 = t * EPT;

    // serial fold of EPT aggregates, keeping running inclusive q[e]
    Xf q[EPT];
    Xf a;
    xf_identity(a);
#pragma unroll
    for (int e = 0; e < EPT; ++e) {
        const int i = i0 + e;
        if (i < nb) a = xf_comb(a, xf_load4(&agg[i]));
        q[e] = a;
    }

    const Xf inc = wave_scan(a, lane);
    if (lane == 63) wagg[w] = inc;
    __syncthreads();

    // cross-wave exclusive prefix (broadcast LDS reads, conflict-free)
    Xf exw;
    xf_identity(exw);
    for (int k = 0; k < w; ++k) exw = xf_comb(exw, wagg[k]);

    // thread-exclusive within wave
    Xf ext = xf_shfl_up(inc, 1);
    Xf T;
    if (lane == 0) T = exw;
    else T = xf_comb(exw, ext);

    // pfx[i0+e] = exclusive prefix of block i0+e
    if (i0 < nb) xf_store4(&pfx[i0], T);
#pragma unroll
    for (int e = 1; e < EPT; ++e) {
        if (i0 + e < nb) {
            Xf v = xf_comb(T, q[e - 1]);
            xf_store4(&pfx[i0 + e], v);
        }
    }
}

// ---------------- Phase 3: recompute local scans, apply prefixes, write out ----------------
__global__ void __launch_bounds__(TPB) fk_phase3(const float* __restrict__ ll,
                                                 const float* __restrict__ th,
                                                 const Xf* __restrict__ pfx,
                                                 float* __restrict__ out, int n) {
    __shared__ Xf wagg[NWAVE];
    const int t = threadIdx.x;
    const int lane = t & 63, w = t >> 6;
    const long long j0 = (long long)blockIdx.x * EPB + (long long)t * EPT;

    Xf a;
    float pe[EPT][3];
    local_fold(ll, th, j0, n, a, pe);

    const Xf inc = wave_scan(a, lane);
    if (lane == 63) wagg[w] = inc;
    __syncthreads();

    Xf exw;
    xf_identity(exw);
    for (int k = 0; k < w; ++k) exw = xf_comb(exw, wagg[k]);

    const Xf ext = xf_shfl_up(inc, 1);

    const Xf G = xf_load4(&pfx[blockIdx.x]);  // uniform per block
    Xf T = xf_comb(G, exw);
    if (lane != 0) T = xf_comb(T, ext);

    write_out(out, j0, n, T, pe);
}

extern "C" void kernel_launch(void* const* d_in, const int* in_sizes, int n_in,
                              void* d_out, int out_size, void* d_ws, size_t ws_size,
                              hipStream_t stream) {
    const float* ll = (const float*)d_in[0];   // link_lengths [N]
    const float* th = (const float*)d_in[1];   // theta [N,3]
    float* out = (float*)d_out;                // [N,3] f32
    const int n = in_sizes[0];

    int nb = (n + EPB - 1) / EPB;              // 1024 for N = 2^20
    if (nb > MAXB) nb = MAXB;

    Xf* agg = (Xf*)d_ws;
    Xf* pfx = agg + MAXB;

    fk_phase1<<<nb, TPB, 0, stream>>>(ll, th, agg, n);
    fk_phase2<<<1, TPB, 0, stream>>>(agg, pfx, nb);
    fk_phase3<<<nb, TPB, 0, stream>>>(ll, th, pfx, out, n);
}